// Round 9
// baseline (577.846 us; speedup 1.0000x reference)
//
#include <hip/hip_runtime.h>
#include <stdint.h>

// Problem: B=64, DIM=512, T=2048, S=1024.
// out[b][s][t] = softmax_s( 2*cross - msq[s] ),  cross = sum_d units[d][s]*H[b][d][t].
// Pipeline:
//   k_prep_units: units fp32 -> Upack hi/lo (MFMA-fragment-slab order) + msq[s].
//   k_prep_h:     H fp32 -> Bpack hi/lo (fragment-slab order per (b, t-group-64)).
//   k_fused:      FULL-S GEMM (1024s x 64t per block; wave tile 128s x 64t) via
//                 mfma_f32_32x32x16_bf16, 3-term hi/lo.
//                 B: whole 128KB block-panel staged in LDS (prologue 64KB + in-loop
//                    64KB, one vmcnt(0)+barrier at k=10 makes it race-free), then
//                    K-loop B = ds_read_b128 only (no global B, no barriers).
//                 A: direct global->VGPR (Upack L2-resident), even/odd reg dbuf.
//                 Reg budget: acc 128 AGPR + 96 VGPR operands + addr ~= 248 <= 256.
//                 In-register softmax epilogue (4KB LDS reductions).
// ws: BpackH[0,128M) BpackL[128M,256M) UpackH(1M) UpackL(1M) msq(4K) => ~258 MB.

typedef unsigned short u16;
typedef __attribute__((ext_vector_type(8))) short short8;    // 8 x bf16 (4 VGPR)
typedef __attribute__((ext_vector_type(4))) float f32x4;
typedef __attribute__((ext_vector_type(16))) float f32x16;   // 32x32 C/D

#define B_DIM 64
#define DIM   512
#define T_DIM 2048
#define S_DIM 1024

// k_fused LDS map
#define B_LO_O 65536
#define REDM_O 131072
#define REDS_O 133120
#define SM_SZ  135168

__device__ __forceinline__ u16 f32_to_bf16(float f) {
  uint32_t u = __float_as_uint(f);
  uint32_t r = u + 0x7FFFu + ((u >> 16) & 1u);   // RNE
  return (u16)(r >> 16);
}
__device__ __forceinline__ float bf16_to_f32(u16 h) {
  return __uint_as_float(((uint32_t)h) << 16);
}

// ---------------- K0a: units -> Upack hi/lo + msq ----------------
__global__ __launch_bounds__(256) void k_prep_units(const float* __restrict__ units,
                                                    u16* __restrict__ UpH, u16* __restrict__ UpL,
                                                    float* __restrict__ msq) {
  const int s0 = blockIdx.x * 4;
  const int tid = threadIdx.x;
  const int lane = tid & 63, wv = tid >> 6;
  float acc0 = 0.f, acc1 = 0.f, acc2 = 0.f, acc3 = 0.f;
#pragma unroll
  for (int j = 0; j < 2; ++j) {
    const int d = tid + j * 256;
    const float4 v = *(const float4*)(units + (size_t)d * S_DIM + s0);
    acc0 += v.x * v.x; acc1 += v.y * v.y; acc2 += v.z * v.z; acc3 += v.w * v.w;
    const int dbase = (d >> 4) * 16384 + ((d >> 3) & 1) * 256 + (d & 7);
    const float fv[4] = {v.x, v.y, v.z, v.w};
#pragma unroll
    for (int q = 0; q < 4; ++q) {
      const int s = s0 + q;
      const int idx = dbase + ((s >> 5) * 64 + (s & 31)) * 8;
      const u16 h = f32_to_bf16(fv[q]);
      UpH[idx] = h;
      UpL[idx] = f32_to_bf16(fv[q] - bf16_to_f32(h));
    }
  }
#pragma unroll
  for (int off = 1; off < 64; off <<= 1) {
    acc0 += __shfl_xor(acc0, off);
    acc1 += __shfl_xor(acc1, off);
    acc2 += __shfl_xor(acc2, off);
    acc3 += __shfl_xor(acc3, off);
  }
  __shared__ float part[4][4];
  if (lane == 0) { part[wv][0] = acc0; part[wv][1] = acc1; part[wv][2] = acc2; part[wv][3] = acc3; }
  __syncthreads();
  if (tid < 4) msq[s0 + tid] = part[0][tid] + part[1][tid] + part[2][tid] + part[3][tid];
}

// ---------------- K0b: H [b][d][t] -> Bpack hi/lo ----------------
__global__ __launch_bounds__(256) void k_prep_h(const float* __restrict__ H,
                                                u16* __restrict__ BpH, u16* __restrict__ BpL) {
  __shared__ float tile[64 * 68];
  const int bx = blockIdx.x;                 // t-group (64 t)
  const int d0 = blockIdx.y * 64;
  const int b = blockIdx.z;
  const int t0 = bx * 64;
  const int tid = threadIdx.x;
#pragma unroll
  for (int j = 0; j < 4; ++j) {
    const int chunk = tid + j * 256;
    const int r = chunk >> 4, c4 = (chunk & 15) * 4;
    const float4 v = *(const float4*)(H + ((size_t)(b * DIM + d0 + r)) * T_DIM + t0 + c4);
    *(float4*)(&tile[r * 68 + c4]) = v;
  }
  __syncthreads();
#pragma unroll
  for (int j = 0; j < 2; ++j) {
    const int chunk = tid + j * 256;
    const int q = chunk >> 3, e8 = (chunk & 7) * 8;   // t-local q, d-local group e8
    union { u16 us[8]; uint4 v4; } hi, lo;
#pragma unroll
    for (int k = 0; k < 8; ++k) {
      const float f = tile[(e8 + k) * 68 + q];
      const u16 h = f32_to_bf16(f);
      hi.us[k] = h;
      lo.us[k] = f32_to_bf16(f - bf16_to_f32(h));
    }
    const int dg = d0 + e8;
    const int chunkB = (q >> 5) * 64 + ((dg >> 3) & 1) * 32 + (q & 31);
    const size_t o = ((((size_t)b * 32 + bx) * 32 + (dg >> 4)) * 128 + chunkB) * 8;
    *(uint4*)(BpH + o) = hi.v4;
    *(uint4*)(BpL + o) = lo.v4;
  }
}

// ---------------- K1: fused GEMM (32x32x16) + softmax ----------------
__device__ __forceinline__ void gl16(const void* g, void* l) {
  __builtin_amdgcn_global_load_lds((const __attribute__((address_space(1))) void*)g,
                                   (__attribute__((address_space(3))) void*)l, 16, 0, 0);
}

#define WAITV0() asm volatile("s_waitcnt vmcnt(0)" ::: "memory")
#define SYNCPT() do { __builtin_amdgcn_s_barrier(); __builtin_amdgcn_sched_barrier(0); } while (0)

__global__ __launch_bounds__(512, 2) void k_fused(const u16* __restrict__ UpH, const u16* __restrict__ UpL,
                                                  const u16* __restrict__ BpH, const u16* __restrict__ BpL,
                                                  const float* __restrict__ msq,
                                                  float* __restrict__ out) {
  __shared__ __align__(16) char sm[SM_SZ];
  const int tid = threadIdx.x;
  const int lane = tid & 63, wv = tid >> 6;
  const int l31 = lane & 31, lhi = lane >> 5;
  const int sw = wv;                 // wave owns s rows [sw*128, +128)

  const int tgx = blockIdx.x;        // 64-t group
  const int t00 = tgx * 64;
  const int bb = blockIdx.y;

  // ---- A: direct-from-global fragment bases (R8-verified) ----
  const char* const aH = (const char*)UpH + (sw * 4) * 1024 + lane * 16;   // + ks*32768 + mt*1024
  const char* const aL = (const char*)UpL + (sw * 4) * 1024 + lane * 16;
  // ---- B: block panel base (contiguous 64KB per hi/lo) ----
  const size_t bgBase = (((size_t)bb * 32 + tgx) * 32) * 2048;
  const char* const pBH = (const char*)BpH + bgBase;
  const char* const pBL = (const char*)BpL + bgBase;

  f32x16 acc[4][2];
#pragma unroll
  for (int mt = 0; mt < 4; ++mt)
#pragma unroll
    for (int nt = 0; nt < 2; ++nt)
#pragma unroll
      for (int r = 0; r < 16; ++r)
        acc[mt][nt][r] = 0.f;

  short8 ah0[4], ah1[4], al0[4], al1[4];
  short8 bh0[2], bh1[2], bl0[2], bl1[2];

#define LD_AH(D, KS) do { const size_t ko = (size_t)(KS) * 32768;            \
    (D)[0] = *(const short8*)(aH + ko);                                      \
    (D)[1] = *(const short8*)(aH + ko + 1024);                               \
    (D)[2] = *(const short8*)(aH + ko + 2048);                               \
    (D)[3] = *(const short8*)(aH + ko + 3072); } while (0)
#define LD_AL(D, KS) do { const size_t ko = (size_t)(KS) * 32768;            \
    (D)[0] = *(const short8*)(aL + ko);                                      \
    (D)[1] = *(const short8*)(aL + ko + 1024);                               \
    (D)[2] = *(const short8*)(aL + ko + 2048);                               \
    (D)[3] = *(const short8*)(aL + ko + 3072); } while (0)
#define DS_B(BH, BL, KS) do { const int bo = (KS) * 2048 + lane * 16;        \
    (BH)[0] = *(const short8*)(sm + bo);                                     \
    (BH)[1] = *(const short8*)(sm + bo + 1024);                              \
    (BL)[0] = *(const short8*)(sm + B_LO_O + bo);                            \
    (BL)[1] = *(const short8*)(sm + B_LO_O + bo + 1024); } while (0)
// stage slab-pair (16+2j, 17+2j): 8KB, 1 inst/wave (waves 0-3 hi, 4-7 lo)
#define STG(J) do { const int off = (16 + 2 * (J)) * 2048 + (wv & 3) * 1024 + lane * 16; \
    if (wv < 4) gl16(pBH + off, sm + off);                                   \
    else        gl16(pBL + off, sm + B_LO_O + off); } while (0)

#define MM8(AF, BF)                                                          \
    __builtin_amdgcn_s_setprio(1);                                           \
    _Pragma("unroll") for (int mt = 0; mt < 4; ++mt)                         \
      _Pragma("unroll") for (int nt = 0; nt < 2; ++nt)                       \
        acc[mt][nt] = __builtin_amdgcn_mfma_f32_32x32x16_bf16((AF)[mt], (BF)[nt], acc[mt][nt], 0, 0, 0); \
    __builtin_amdgcn_s_setprio(0);

  // ---- prologue: stage B slabs 0..15 (8 insts/thread), A slab 0/1 regs ----
#pragma unroll
  for (int r = 0; r < 4; ++r) {
    const int off = (tid + r * 512) * 16;          // [0, 32768)
    gl16(pBH + off, sm + off);
    gl16(pBL + off, sm + B_LO_O + off);
  }
  LD_AH(ah0, 0); LD_AL(al0, 0);
  WAITV0();
  SYNCPT();                                        // B(0..15) in LDS
  DS_B(bh0, bl0, 0);
  LD_AH(ah1, 1); LD_AL(al1, 1);
  DS_B(bh1, bl1, 1);

#pragma unroll 1
  for (int k = 0; k < 32; k += 2) {
    if (k == 10) { WAITV0(); SYNCPT(); }           // B(16..31) staged (issued k<=7) -> visible
    const int kc2 = (k + 2 < 32) ? (k + 2) : 31;
    const int kc3 = (k + 3 < 32) ? (k + 3) : 31;
    // ---- even slab k: set0 ----
    if (k < 8) STG(k);
    MM8(ah0, bh0);
    MM8(ah0, bl0);
    MM8(al0, bh0);
    LD_AH(ah0, kc2); LD_AL(al0, kc2); DS_B(bh0, bl0, kc2);
    // ---- odd slab k+1: set1 ----
    if (k + 1 < 8) STG(k + 1);
    MM8(ah1, bh1);
    MM8(ah1, bl1);
    MM8(al1, bh1);
    LD_AH(ah1, kc3); LD_AL(al1, kc3); DS_B(bh1, bl1, kc3);
  }

  // ---- epilogue: softmax over s, in registers (R6/R8-verified C/D mapping) ----
  // s = sw*128 + mt*32 + lhi*4 + q*8 + r (reg=q*4+r); t = t00 + nt*32 + l31.
  float* redM = (float*)(sm + REDM_O);   // [8][64]
  float* redS = (float*)(sm + REDS_O);
  float mx0 = -3.0e38f, mx1 = -3.0e38f;
#pragma unroll
  for (int mt = 0; mt < 4; ++mt) {
    const int sb = sw * 128 + mt * 32 + lhi * 4;
#pragma unroll
    for (int q = 0; q < 4; ++q) {
      const f32x4 mq = *(const f32x4*)(msq + sb + q * 8);
#pragma unroll
      for (int r = 0; r < 4; ++r) {
        const int reg = q * 4 + r;
        const float v0 = 2.f * acc[mt][0][reg] - mq[r];
        const float v1 = 2.f * acc[mt][1][reg] - mq[r];
        acc[mt][0][reg] = v0; acc[mt][1][reg] = v1;
        mx0 = fmaxf(mx0, v0); mx1 = fmaxf(mx1, v1);
      }
    }
  }
  mx0 = fmaxf(mx0, __shfl_xor(mx0, 32));
  mx1 = fmaxf(mx1, __shfl_xor(mx1, 32));
  if (lane < 32) { redM[wv * 64 + l31] = mx0; redM[wv * 64 + 32 + l31] = mx1; }
  __syncthreads();
  float M0 = redM[l31], M1 = redM[32 + l31];
#pragma unroll
  for (int w = 1; w < 8; ++w) {
    M0 = fmaxf(M0, redM[w * 64 + l31]);
    M1 = fmaxf(M1, redM[w * 64 + 32 + l31]);
  }
  float s0 = 0.f, s1 = 0.f;
#pragma unroll
  for (int mt = 0; mt < 4; ++mt)
#pragma unroll
    for (int reg = 0; reg < 16; ++reg) {
      const float e0 = __expf(acc[mt][0][reg] - M0);
      const float e1 = __expf(acc[mt][1][reg] - M1);
      acc[mt][0][reg] = e0; acc[mt][1][reg] = e1;
      s0 += e0; s1 += e1;
    }
  s0 += __shfl_xor(s0, 32);
  s1 += __shfl_xor(s1, 32);
  if (lane < 32) { redS[wv * 64 + l31] = s0; redS[wv * 64 + 32 + l31] = s1; }
  __syncthreads();
  float S0 = redS[l31], S1 = redS[32 + l31];
#pragma unroll
  for (int w = 1; w < 8; ++w) {
    S0 += redS[w * 64 + l31];
    S1 += redS[w * 64 + 32 + l31];
  }
  const float r0 = 1.0f / S0, r1 = 1.0f / S1;

  float* const outb = out + ((size_t)bb << 21);   // b * 1024 * 2048
  const int tc0 = t00 + l31, tc1 = t00 + 32 + l31;
#pragma unroll
  for (int mt = 0; mt < 4; ++mt) {
    const int sb = sw * 128 + mt * 32 + lhi * 4;
#pragma unroll
    for (int q = 0; q < 4; ++q)
#pragma unroll
      for (int r = 0; r < 4; ++r) {
        const int srow = sb + q * 8 + r;
        const int reg = q * 4 + r;
        outb[(size_t)srow * T_DIM + tc0] = acc[mt][0][reg] * r0;
        outb[(size_t)srow * T_DIM + tc1] = acc[mt][1][reg] * r1;
      }
  }
}

// ---------------- launch ----------------
extern "C" void kernel_launch(void* const* d_in, const int* in_sizes, int n_in,
                              void* d_out, int out_size, void* d_ws, size_t ws_size,
                              hipStream_t stream) {
  (void)in_sizes; (void)n_in; (void)out_size; (void)ws_size;
  const float* H = (const float*)d_in[0];
  const float* units = (const float*)d_in[1];
  float* out = (float*)d_out;
  char* ws = (char*)d_ws;
  u16* BpH = (u16*)(ws);
  u16* BpL = (u16*)(ws + 134217728);
  u16* UpH = (u16*)(ws + 268435456);
  u16* UpL = (u16*)(ws + 269484032);
  float* msq = (float*)(ws + 270532608);

  k_prep_units<<<dim3(S_DIM / 4), 256, 0, stream>>>(units, UpH, UpL, msq);
  k_prep_h<<<dim3(T_DIM / 64, DIM / 64, B_DIM), 256, 0, stream>>>(H, BpH, BpL);
  k_fused<<<dim3(T_DIM / 64, B_DIM), 512, 0, stream>>>(UpH, UpL, BpH, BpL, msq, out);
}

// Round 10
// 560.352 us; speedup vs baseline: 1.0312x; 1.0312x over previous
//
#include <hip/hip_runtime.h>
#include <stdint.h>

// Problem: B=64, DIM=512, T=2048, S=1024.
// out[b][s][t] = softmax_s( 2*cross - msq[s] ),  cross = sum_d units[d][s]*H[b][d][t].
// Pipeline:
//   k_prep_units: units fp32 -> Upack hi/lo (MFMA-fragment-slab order) + msq[s].
//   k_prep_h:     H fp32 -> Bpack hi/lo (fragment-slab order per (b, t-group-64)).
//   k_fused:      FULL-S GEMM (1024s x 64t per block; wave tile 128s x 64t),
//                 mfma_f32_32x32x16_bf16, 3-term hi/lo.
//                 m201-style phase-locked K-loop: per slab one s_barrier +
//                 counted vmcnt (8/9, never 0 until last slab), ds_read B from
//                 write-once LDS panel, A direct global->VGPR 2-slab prefetch.
//                 In-register softmax epilogue.
// ws: BpackH[0,128M) BpackL[128M,256M) UpackH(1M) UpackL(1M) msq(4K) => ~258 MB.

typedef unsigned short u16;
typedef __attribute__((ext_vector_type(8))) short short8;    // 8 x bf16 (4 VGPR)
typedef __attribute__((ext_vector_type(4))) float f32x4;
typedef __attribute__((ext_vector_type(16))) float f32x16;   // 32x32 C/D

#define B_DIM 64
#define DIM   512
#define T_DIM 2048
#define S_DIM 1024

// k_fused LDS map
#define B_LO_O 65536
#define REDM_O 131072
#define REDS_O 133120
#define SM_SZ  135168

__device__ __forceinline__ u16 f32_to_bf16(float f) {
  uint32_t u = __float_as_uint(f);
  uint32_t r = u + 0x7FFFu + ((u >> 16) & 1u);   // RNE
  return (u16)(r >> 16);
}
__device__ __forceinline__ float bf16_to_f32(u16 h) {
  return __uint_as_float(((uint32_t)h) << 16);
}

// ---------------- K0a: units -> Upack hi/lo + msq ----------------
__global__ __launch_bounds__(256) void k_prep_units(const float* __restrict__ units,
                                                    u16* __restrict__ UpH, u16* __restrict__ UpL,
                                                    float* __restrict__ msq) {
  const int s0 = blockIdx.x * 4;
  const int tid = threadIdx.x;
  const int lane = tid & 63, wv = tid >> 6;
  float acc0 = 0.f, acc1 = 0.f, acc2 = 0.f, acc3 = 0.f;
#pragma unroll
  for (int j = 0; j < 2; ++j) {
    const int d = tid + j * 256;
    const float4 v = *(const float4*)(units + (size_t)d * S_DIM + s0);
    acc0 += v.x * v.x; acc1 += v.y * v.y; acc2 += v.z * v.z; acc3 += v.w * v.w;
    const int dbase = (d >> 4) * 16384 + ((d >> 3) & 1) * 256 + (d & 7);
    const float fv[4] = {v.x, v.y, v.z, v.w};
#pragma unroll
    for (int q = 0; q < 4; ++q) {
      const int s = s0 + q;
      const int idx = dbase + ((s >> 5) * 64 + (s & 31)) * 8;
      const u16 h = f32_to_bf16(fv[q]);
      UpH[idx] = h;
      UpL[idx] = f32_to_bf16(fv[q] - bf16_to_f32(h));
    }
  }
#pragma unroll
  for (int off = 1; off < 64; off <<= 1) {
    acc0 += __shfl_xor(acc0, off);
    acc1 += __shfl_xor(acc1, off);
    acc2 += __shfl_xor(acc2, off);
    acc3 += __shfl_xor(acc3, off);
  }
  __shared__ float part[4][4];
  if (lane == 0) { part[wv][0] = acc0; part[wv][1] = acc1; part[wv][2] = acc2; part[wv][3] = acc3; }
  __syncthreads();
  if (tid < 4) msq[s0 + tid] = part[0][tid] + part[1][tid] + part[2][tid] + part[3][tid];
}

// ---------------- K0b: H [b][d][t] -> Bpack hi/lo ----------------
__global__ __launch_bounds__(256) void k_prep_h(const float* __restrict__ H,
                                                u16* __restrict__ BpH, u16* __restrict__ BpL) {
  __shared__ float tile[64 * 68];
  const int bx = blockIdx.x;                 // t-group (64 t)
  const int d0 = blockIdx.y * 64;
  const int b = blockIdx.z;
  const int t0 = bx * 64;
  const int tid = threadIdx.x;
#pragma unroll
  for (int j = 0; j < 4; ++j) {
    const int chunk = tid + j * 256;
    const int r = chunk >> 4, c4 = (chunk & 15) * 4;
    const float4 v = *(const float4*)(H + ((size_t)(b * DIM + d0 + r)) * T_DIM + t0 + c4);
    *(float4*)(&tile[r * 68 + c4]) = v;
  }
  __syncthreads();
#pragma unroll
  for (int j = 0; j < 2; ++j) {
    const int chunk = tid + j * 256;
    const int q = chunk >> 3, e8 = (chunk & 7) * 8;   // t-local q, d-local group e8
    union { u16 us[8]; uint4 v4; } hi, lo;
#pragma unroll
    for (int k = 0; k < 8; ++k) {
      const float f = tile[(e8 + k) * 68 + q];
      const u16 h = f32_to_bf16(f);
      hi.us[k] = h;
      lo.us[k] = f32_to_bf16(f - bf16_to_f32(h));
    }
    const int dg = d0 + e8;
    const int chunkB = (q >> 5) * 64 + ((dg >> 3) & 1) * 32 + (q & 31);
    const size_t o = ((((size_t)b * 32 + bx) * 32 + (dg >> 4)) * 128 + chunkB) * 8;
    *(uint4*)(BpH + o) = hi.v4;
    *(uint4*)(BpL + o) = lo.v4;
  }
}

// ---------------- K1: fused GEMM (32x32x16) + softmax ----------------
__device__ __forceinline__ void gl16(const void* g, void* l) {
  __builtin_amdgcn_global_load_lds((const __attribute__((address_space(1))) void*)g,
                                   (__attribute__((address_space(3))) void*)l, 16, 0, 0);
}

#define WAITV(N) asm volatile("s_waitcnt vmcnt(" #N ")" ::: "memory")
#define SYNCPT() do { __builtin_amdgcn_s_barrier(); __builtin_amdgcn_sched_barrier(0); } while (0)
#define LGKM0()  do { asm volatile("s_waitcnt lgkmcnt(0)" ::: "memory"); __builtin_amdgcn_sched_barrier(0); } while (0)

__global__ __launch_bounds__(512, 2) void k_fused(const u16* __restrict__ UpH, const u16* __restrict__ UpL,
                                                  const u16* __restrict__ BpH, const u16* __restrict__ BpL,
                                                  const float* __restrict__ msq,
                                                  float* __restrict__ out) {
  __shared__ __align__(16) char sm[SM_SZ];
  const int tid = threadIdx.x;
  const int lane = tid & 63, wv = tid >> 6;
  const int l31 = lane & 31, lhi = lane >> 5;
  const int sw = wv;                 // wave owns s rows [sw*128, +128)

  const int tgx = blockIdx.x;        // 64-t group
  const int t00 = tgx * 64;
  const int bb = blockIdx.y;

  // ---- A: direct-from-global fragment bases (R8/R9-verified) ----
  const char* const aH = (const char*)UpH + (sw * 4) * 1024 + lane * 16;   // + ks*32768 + mt*1024
  const char* const aL = (const char*)UpL + (sw * 4) * 1024 + lane * 16;
  // ---- B: block panel base (contiguous 64KB per hi/lo) ----
  const size_t bgBase = (((size_t)bb * 32 + tgx) * 32) * 2048;
  const char* const pBH = (const char*)BpH + bgBase;
  const char* const pBL = (const char*)BpL + bgBase;

  f32x16 acc[4][2];
#pragma unroll
  for (int mt = 0; mt < 4; ++mt)
#pragma unroll
    for (int nt = 0; nt < 2; ++nt)
#pragma unroll
      for (int r = 0; r < 16; ++r)
        acc[mt][nt][r] = 0.f;

  short8 ah0[4], ah1[4], al0[4], al1[4];
  short8 bh[2], bl[2];

#define LD_AH(D, KS) do { const size_t ko = (size_t)(KS) * 32768;            \
    (D)[0] = *(const short8*)(aH + ko);                                      \
    (D)[1] = *(const short8*)(aH + ko + 1024);                               \
    (D)[2] = *(const short8*)(aH + ko + 2048);                               \
    (D)[3] = *(const short8*)(aH + ko + 3072); } while (0)
#define LD_AL(D, KS) do { const size_t ko = (size_t)(KS) * 32768;            \
    (D)[0] = *(const short8*)(aL + ko);                                      \
    (D)[1] = *(const short8*)(aL + ko + 1024);                               \
    (D)[2] = *(const short8*)(aL + ko + 2048);                               \
    (D)[3] = *(const short8*)(aL + ko + 3072); } while (0)
#define DS_B(KS) do { const int bo = (KS) * 2048 + lane * 16;                \
    bh[0] = *(const short8*)(sm + bo);                                       \
    bh[1] = *(const short8*)(sm + bo + 1024);                                \
    bl[0] = *(const short8*)(sm + B_LO_O + bo);                              \
    bl[1] = *(const short8*)(sm + B_LO_O + bo + 1024); } while (0)
// stage slab-pair (16+2k, 17+2k): 8KB, 1 inst/thread (waves 0-3 hi, 4-7 lo)
#define STG(K) do { const int off = (16 + 2 * (K)) * 2048 + (wv & 3) * 1024 + lane * 16; \
    if (wv < 4) gl16(pBH + off, sm + off);                                   \
    else        gl16(pBL + off, sm + B_LO_O + off); } while (0)

#define MM8(AF, BF)                                                          \
    __builtin_amdgcn_s_setprio(1);                                           \
    _Pragma("unroll") for (int mt = 0; mt < 4; ++mt)                         \
      _Pragma("unroll") for (int nt = 0; nt < 2; ++nt)                       \
        acc[mt][nt] = __builtin_amdgcn_mfma_f32_32x32x16_bf16((AF)[mt], (BF)[nt], acc[mt][nt], 0, 0, 0); \
    __builtin_amdgcn_s_setprio(0);

// one slab: barrier-locked phase; A(K+2) loads slotted after their set's last use
#define SLAB(K, AH, AL, DO_STG, DO_LD) do {                                  \
    SYNCPT();                                                                \
    DS_B(K);                                                                 \
    if (DO_STG) STG(K);                                                      \
    LGKM0();                                                                 \
    MM8(AH, bh);                                                             \
    MM8(AH, bl);                                                             \
    if (DO_LD) LD_AH(AH, (K) + 2);                                           \
    MM8(AL, bh);                                                             \
    if (DO_LD) LD_AL(AL, (K) + 2);                                           \
  } while (0)

  // ---- prologue: stage B slabs 0..15 (8 vm insts), A(0),A(1) regs (16 vm) ----
#pragma unroll
  for (int r = 0; r < 4; ++r) {
    const int off = (tid + r * 512) * 16;          // [0, 32768)
    gl16(pBH + off, sm + off);
    gl16(pBL + off, sm + B_LO_O + off);
  }
  LD_AH(ah0, 0); LD_AL(al0, 0);
  LD_AH(ah1, 1); LD_AL(al1, 1);
  WAITV(16);                                       // B panel first half + staged; A(0),A(1) in flight

  // ---- phase-locked K-loop; vmcnt ladder: 8 / 9(while STG in stream) / 8 / 0 ----
  WAITV(8);  SLAB(0, ah0, al0, true, true);
  WAITV(9);  SLAB(1, ah1, al1, true, true);
#pragma unroll 1
  for (int k = 2; k < 8; k += 2) {
    WAITV(9);  SLAB(k,     ah0, al0, true, true);
    WAITV(9);  SLAB(k + 1, ah1, al1, true, true);
  }
  WAITV(9);  SLAB(8, ah0, al0, false, true);
#pragma unroll 1
  for (int k = 9; k < 29; k += 2) {
    WAITV(8);  SLAB(k,     ah1, al1, false, true);
    WAITV(8);  SLAB(k + 1, ah0, al0, false, true);
  }
  WAITV(8);  SLAB(29, ah1, al1, false, true);      // loads A(31)
  WAITV(8);  SLAB(30, ah0, al0, false, false);
  WAITV(0);  SLAB(31, ah1, al1, false, false);

  // ---- epilogue: softmax over s, in registers (R6/R8-verified C/D mapping) ----
  // s = sw*128 + mt*32 + lhi*4 + q*8 + r (reg=q*4+r); t = t00 + nt*32 + l31.
  float* redM = (float*)(sm + REDM_O);   // [8][64]
  float* redS = (float*)(sm + REDS_O);
  float mx0 = -3.0e38f, mx1 = -3.0e38f;
#pragma unroll
  for (int mt = 0; mt < 4; ++mt) {
    const int sb = sw * 128 + mt * 32 + lhi * 4;
#pragma unroll
    for (int q = 0; q < 4; ++q) {
      const f32x4 mq = *(const f32x4*)(msq + sb + q * 8);
#pragma unroll
      for (int r = 0; r < 4; ++r) {
        const int reg = q * 4 + r;
        const float v0 = 2.f * acc[mt][0][reg] - mq[r];
        const float v1 = 2.f * acc[mt][1][reg] - mq[r];
        acc[mt][0][reg] = v0; acc[mt][1][reg] = v1;
        mx0 = fmaxf(mx0, v0); mx1 = fmaxf(mx1, v1);
      }
    }
  }
  mx0 = fmaxf(mx0, __shfl_xor(mx0, 32));
  mx1 = fmaxf(mx1, __shfl_xor(mx1, 32));
  if (lane < 32) { redM[wv * 64 + l31] = mx0; redM[wv * 64 + 32 + l31] = mx1; }
  __syncthreads();
  float M0 = redM[l31], M1 = redM[32 + l31];
#pragma unroll
  for (int w = 1; w < 8; ++w) {
    M0 = fmaxf(M0, redM[w * 64 + l31]);
    M1 = fmaxf(M1, redM[w * 64 + 32 + l31]);
  }
  float s0 = 0.f, s1 = 0.f;
#pragma unroll
  for (int mt = 0; mt < 4; ++mt)
#pragma unroll
    for (int reg = 0; reg < 16; ++reg) {
      const float e0 = __expf(acc[mt][0][reg] - M0);
      const float e1 = __expf(acc[mt][1][reg] - M1);
      acc[mt][0][reg] = e0; acc[mt][1][reg] = e1;
      s0 += e0; s1 += e1;
    }
  s0 += __shfl_xor(s0, 32);
  s1 += __shfl_xor(s1, 32);
  if (lane < 32) { redS[wv * 64 + l31] = s0; redS[wv * 64 + 32 + l31] = s1; }
  __syncthreads();
  float S0 = redS[l31], S1 = redS[32 + l31];
#pragma unroll
  for (int w = 1; w < 8; ++w) {
    S0 += redS[w * 64 + l31];
    S1 += redS[w * 64 + 32 + l31];
  }
  const float r0 = 1.0f / S0, r1 = 1.0f / S1;

  float* const outb = out + ((size_t)bb << 21);   // b * 1024 * 2048
  const int tc0 = t00 + l31, tc1 = t00 + 32 + l31;
#pragma unroll
  for (int mt = 0; mt < 4; ++mt) {
    const int sb = sw * 128 + mt * 32 + lhi * 4;
#pragma unroll
    for (int q = 0; q < 4; ++q)
#pragma unroll
      for (int r = 0; r < 4; ++r) {
        const int srow = sb + q * 8 + r;
        const int reg = q * 4 + r;
        outb[(size_t)srow * T_DIM + tc0] = acc[mt][0][reg] * r0;
        outb[(size_t)srow * T_DIM + tc1] = acc[mt][1][reg] * r1;
      }
  }
}

// ---------------- launch ----------------
extern "C" void kernel_launch(void* const* d_in, const int* in_sizes, int n_in,
                              void* d_out, int out_size, void* d_ws, size_t ws_size,
                              hipStream_t stream) {
  (void)in_sizes; (void)n_in; (void)out_size; (void)ws_size;
  const float* H = (const float*)d_in[0];
  const float* units = (const float*)d_in[1];
  float* out = (float*)d_out;
  char* ws = (char*)d_ws;
  u16* BpH = (u16*)(ws);
  u16* BpL = (u16*)(ws + 134217728);
  u16* UpH = (u16*)(ws + 268435456);
  u16* UpL = (u16*)(ws + 269484032);
  float* msq = (float*)(ws + 270532608);

  k_prep_units<<<dim3(S_DIM / 4), 256, 0, stream>>>(units, UpH, UpL, msq);
  k_prep_h<<<dim3(T_DIM / 64, DIM / 64, B_DIM), 256, 0, stream>>>(H, BpH, BpL);
  k_fused<<<dim3(T_DIM / 64, B_DIM), 512, 0, stream>>>(UpH, UpL, BpH, BpL, msq, out);
}

// Round 11
// 559.083 us; speedup vs baseline: 1.0336x; 1.0023x over previous
//
#include <hip/hip_runtime.h>
#include <stdint.h>

// Problem: B=64, DIM=512, T=2048, S=1024.
// out[b][s][t] = softmax_s( 2*cross - msq[s] ),  cross = sum_d units[d][s]*H[b][d][t].
// Pipeline:
//   k_prep_units: units fp32 -> Upack hi/lo (MFMA-fragment-slab order) + msq[s].
//   k_prep_h:     H fp32 -> Bpack hi/lo (fragment-slab order per (b, t-group-64)).
//   k_fused:      FULL-S GEMM (1024s x 64t per block; wave tile 128s x 64t),
//                 mfma_f32_32x32x16_bf16, 3-term hi/lo.
//                 16 phases x 2 slabs (BK=32): per phase one barrier + one lgkm
//                 drain + 48 MFMA; A direct global->VGPR with uniform counted
//                 vmcnt ladder WAITV(13)/WAITV(12) (in-order VMEM, never < 12
//                 until tail); B = write-once 128KB LDS panel (ds_read only).
//                 In-register softmax epilogue.
// ws: BpackH[0,128M) BpackL[128M,256M) UpackH(1M) UpackL(1M) msq(4K) => ~258 MB.

typedef unsigned short u16;
typedef __attribute__((ext_vector_type(8))) short short8;    // 8 x bf16 (4 VGPR)
typedef __attribute__((ext_vector_type(4))) float f32x4;
typedef __attribute__((ext_vector_type(16))) float f32x16;   // 32x32 C/D

#define B_DIM 64
#define DIM   512
#define T_DIM 2048
#define S_DIM 1024

// k_fused LDS map
#define B_LO_O 65536
#define REDM_O 131072
#define REDS_O 133120
#define SM_SZ  135168

__device__ __forceinline__ u16 f32_to_bf16(float f) {
  uint32_t u = __float_as_uint(f);
  uint32_t r = u + 0x7FFFu + ((u >> 16) & 1u);   // RNE
  return (u16)(r >> 16);
}
__device__ __forceinline__ float bf16_to_f32(u16 h) {
  return __uint_as_float(((uint32_t)h) << 16);
}

// ---------------- K0a: units -> Upack hi/lo + msq ----------------
__global__ __launch_bounds__(256) void k_prep_units(const float* __restrict__ units,
                                                    u16* __restrict__ UpH, u16* __restrict__ UpL,
                                                    float* __restrict__ msq) {
  const int s0 = blockIdx.x * 4;
  const int tid = threadIdx.x;
  const int lane = tid & 63, wv = tid >> 6;
  float acc0 = 0.f, acc1 = 0.f, acc2 = 0.f, acc3 = 0.f;
#pragma unroll
  for (int j = 0; j < 2; ++j) {
    const int d = tid + j * 256;
    const float4 v = *(const float4*)(units + (size_t)d * S_DIM + s0);
    acc0 += v.x * v.x; acc1 += v.y * v.y; acc2 += v.z * v.z; acc3 += v.w * v.w;
    const int dbase = (d >> 4) * 16384 + ((d >> 3) & 1) * 256 + (d & 7);
    const float fv[4] = {v.x, v.y, v.z, v.w};
#pragma unroll
    for (int q = 0; q < 4; ++q) {
      const int s = s0 + q;
      const int idx = dbase + ((s >> 5) * 64 + (s & 31)) * 8;
      const u16 h = f32_to_bf16(fv[q]);
      UpH[idx] = h;
      UpL[idx] = f32_to_bf16(fv[q] - bf16_to_f32(h));
    }
  }
#pragma unroll
  for (int off = 1; off < 64; off <<= 1) {
    acc0 += __shfl_xor(acc0, off);
    acc1 += __shfl_xor(acc1, off);
    acc2 += __shfl_xor(acc2, off);
    acc3 += __shfl_xor(acc3, off);
  }
  __shared__ float part[4][4];
  if (lane == 0) { part[wv][0] = acc0; part[wv][1] = acc1; part[wv][2] = acc2; part[wv][3] = acc3; }
  __syncthreads();
  if (tid < 4) msq[s0 + tid] = part[0][tid] + part[1][tid] + part[2][tid] + part[3][tid];
}

// ---------------- K0b: H [b][d][t] -> Bpack hi/lo ----------------
__global__ __launch_bounds__(256) void k_prep_h(const float* __restrict__ H,
                                                u16* __restrict__ BpH, u16* __restrict__ BpL) {
  __shared__ float tile[64 * 68];
  const int bx = blockIdx.x;                 // t-group (64 t)
  const int d0 = blockIdx.y * 64;
  const int b = blockIdx.z;
  const int t0 = bx * 64;
  const int tid = threadIdx.x;
#pragma unroll
  for (int j = 0; j < 4; ++j) {
    const int chunk = tid + j * 256;
    const int r = chunk >> 4, c4 = (chunk & 15) * 4;
    const float4 v = *(const float4*)(H + ((size_t)(b * DIM + d0 + r)) * T_DIM + t0 + c4);
    *(float4*)(&tile[r * 68 + c4]) = v;
  }
  __syncthreads();
#pragma unroll
  for (int j = 0; j < 2; ++j) {
    const int chunk = tid + j * 256;
    const int q = chunk >> 3, e8 = (chunk & 7) * 8;   // t-local q, d-local group e8
    union { u16 us[8]; uint4 v4; } hi, lo;
#pragma unroll
    for (int k = 0; k < 8; ++k) {
      const float f = tile[(e8 + k) * 68 + q];
      const u16 h = f32_to_bf16(f);
      hi.us[k] = h;
      lo.us[k] = f32_to_bf16(f - bf16_to_f32(h));
    }
    const int dg = d0 + e8;
    const int chunkB = (q >> 5) * 64 + ((dg >> 3) & 1) * 32 + (q & 31);
    const size_t o = ((((size_t)b * 32 + bx) * 32 + (dg >> 4)) * 128 + chunkB) * 8;
    *(uint4*)(BpH + o) = hi.v4;
    *(uint4*)(BpL + o) = lo.v4;
  }
}

// ---------------- K1: fused GEMM (32x32x16) + softmax ----------------
__device__ __forceinline__ void gl16(const void* g, void* l) {
  __builtin_amdgcn_global_load_lds((const __attribute__((address_space(1))) void*)g,
                                   (__attribute__((address_space(3))) void*)l, 16, 0, 0);
}

#define WAITV(N) asm volatile("s_waitcnt vmcnt(" #N ")" ::: "memory")
#define SYNCPT() do { __builtin_amdgcn_s_barrier(); __builtin_amdgcn_sched_barrier(0); } while (0)
#define LGKM0()  do { asm volatile("s_waitcnt lgkmcnt(0)" ::: "memory"); __builtin_amdgcn_sched_barrier(0); } while (0)

__global__ __launch_bounds__(512, 2) void k_fused(const u16* __restrict__ UpH, const u16* __restrict__ UpL,
                                                  const u16* __restrict__ BpH, const u16* __restrict__ BpL,
                                                  const float* __restrict__ msq,
                                                  float* __restrict__ out) {
  __shared__ __align__(16) char sm[SM_SZ];
  const int tid = threadIdx.x;
  const int lane = tid & 63, wv = tid >> 6;
  const int l31 = lane & 31, lhi = lane >> 5;
  const int sw = wv;                 // wave owns s rows [sw*128, +128)

  const int tgx = blockIdx.x;        // 64-t group
  const int t00 = tgx * 64;
  const int bb = blockIdx.y;

  // ---- A: direct-from-global fragment bases (R8/R9/R10-verified) ----
  const char* const aH = (const char*)UpH + (sw * 4) * 1024 + lane * 16;   // + ks*32768 + mt*1024
  const char* const aL = (const char*)UpL + (sw * 4) * 1024 + lane * 16;
  // ---- B: block panel base (contiguous 64KB per hi/lo) ----
  const size_t bgBase = (((size_t)bb * 32 + tgx) * 32) * 2048;
  const char* const pBH = (const char*)BpH + bgBase;
  const char* const pBL = (const char*)BpL + bgBase;

  f32x16 acc[4][2];
#pragma unroll
  for (int mt = 0; mt < 4; ++mt)
#pragma unroll
    for (int nt = 0; nt < 2; ++nt)
#pragma unroll
      for (int r = 0; r < 16; ++r)
        acc[mt][nt][r] = 0.f;

  short8 ahA[4], alA[4], ahB[4], alB[4];
  short8 bhA[2], blA[2], bhB[2], blB[2];

#define LD_AH(D, KS) do { const size_t ko = (size_t)(KS) * 32768;            \
    (D)[0] = *(const short8*)(aH + ko);                                      \
    (D)[1] = *(const short8*)(aH + ko + 1024);                               \
    (D)[2] = *(const short8*)(aH + ko + 2048);                               \
    (D)[3] = *(const short8*)(aH + ko + 3072); } while (0)
#define LD_AL(D, KS) do { const size_t ko = (size_t)(KS) * 32768;            \
    (D)[0] = *(const short8*)(aL + ko);                                      \
    (D)[1] = *(const short8*)(aL + ko + 1024);                               \
    (D)[2] = *(const short8*)(aL + ko + 2048);                               \
    (D)[3] = *(const short8*)(aL + ko + 3072); } while (0)
#define DS_B2(BH, BL, KS) do { const int bo = (KS) * 2048 + lane * 16;       \
    (BH)[0] = *(const short8*)(sm + bo);                                     \
    (BH)[1] = *(const short8*)(sm + bo + 1024);                              \
    (BL)[0] = *(const short8*)(sm + B_LO_O + bo);                            \
    (BL)[1] = *(const short8*)(sm + B_LO_O + bo + 1024); } while (0)
// stage slab-pair (16+2J, 17+2J): 8KB total, 1 inst/thread
#define STG(J) do { const int off = (16 + 2 * (J)) * 2048 + (wv & 3) * 1024 + lane * 16; \
    if (wv < 4) gl16(pBH + off, sm + off);                                   \
    else        gl16(pBL + off, sm + B_LO_O + off); } while (0)

#define MM8(AF, BF)                                                          \
    __builtin_amdgcn_s_setprio(1);                                           \
    _Pragma("unroll") for (int mt = 0; mt < 4; ++mt)                         \
      _Pragma("unroll") for (int nt = 0; nt < 2; ++nt)                       \
        acc[mt][nt] = __builtin_amdgcn_mfma_f32_32x32x16_bf16((AF)[mt], (BF)[nt], acc[mt][nt], 0, 0, 0); \
    __builtin_amdgcn_s_setprio(0);

// One phase = slabs (2J, 2J+1). Uniform in-order vmcnt ladder:
// entry outstanding = [STG(J-1)?, A(J): ahA4 alA4 ahB4 alB4]; +STG(J) if DO_STG.
// WAITV(WN) before each cluster drains exactly the operand set it needs.
#define PHASE(J, DO_STG, WN) do {                                            \
    const int s0_ = 2 * (J), s1_ = 2 * (J) + 1;                              \
    const int p0_ = (s0_ + 2 < 32) ? s0_ + 2 : 31;                           \
    const int p1_ = (s1_ + 2 < 32) ? s1_ + 2 : 31;                           \
    SYNCPT();                                                                \
    DS_B2(bhA, blA, s0_);                                                    \
    DS_B2(bhB, blB, s1_);                                                    \
    if (DO_STG) STG(J);                                                      \
    LGKM0();                                                                 \
    WAITV(WN);                                                               \
    MM8(ahA, bhA);                                                           \
    MM8(ahA, blA);                                                           \
    LD_AH(ahA, p0_);                                                         \
    WAITV(WN);                                                               \
    MM8(alA, bhA);                                                           \
    LD_AL(alA, p0_);                                                         \
    WAITV(WN);                                                               \
    MM8(ahB, bhB);                                                           \
    MM8(ahB, blB);                                                           \
    LD_AH(ahB, p1_);                                                         \
    WAITV(WN);                                                               \
    MM8(alB, bhB);                                                           \
    LD_AL(alB, p1_);                                                         \
  } while (0)

  // ---- prologue: stage B slabs 0..15 (8 vm insts), A(phase0) regs (16 vm) ----
#pragma unroll
  for (int r = 0; r < 4; ++r) {
    const int off = (tid + r * 512) * 16;          // [0, 32768)
    gl16(pBH + off, sm + off);
    gl16(pBL + off, sm + B_LO_O + off);
  }
  LD_AH(ahA, 0); LD_AL(alA, 0);
  LD_AH(ahB, 1); LD_AL(alB, 1);
  WAITV(16);                                       // B panel landed; A(0) 16 in flight

  PHASE(0, true, 13);
#pragma unroll 1
  for (int j = 1; j < 8; ++j) PHASE(j, true, 13);
#pragma unroll 1
  for (int j = 8; j < 16; ++j) PHASE(j, false, 12);

  // ---- epilogue: softmax over s, in registers (R6/R8-verified C/D mapping) ----
  // s = sw*128 + mt*32 + lhi*4 + q*8 + r (reg=q*4+r); t = t00 + nt*32 + l31.
  float* redM = (float*)(sm + REDM_O);   // [8][64]
  float* redS = (float*)(sm + REDS_O);
  float mx0 = -3.0e38f, mx1 = -3.0e38f;
#pragma unroll
  for (int mt = 0; mt < 4; ++mt) {
    const int sb = sw * 128 + mt * 32 + lhi * 4;
#pragma unroll
    for (int q = 0; q < 4; ++q) {
      const f32x4 mq = *(const f32x4*)(msq + sb + q * 8);
#pragma unroll
      for (int r = 0; r < 4; ++r) {
        const int reg = q * 4 + r;
        const float v0 = 2.f * acc[mt][0][reg] - mq[r];
        const float v1 = 2.f * acc[mt][1][reg] - mq[r];
        acc[mt][0][reg] = v0; acc[mt][1][reg] = v1;
        mx0 = fmaxf(mx0, v0); mx1 = fmaxf(mx1, v1);
      }
    }
  }
  mx0 = fmaxf(mx0, __shfl_xor(mx0, 32));
  mx1 = fmaxf(mx1, __shfl_xor(mx1, 32));
  if (lane < 32) { redM[wv * 64 + l31] = mx0; redM[wv * 64 + 32 + l31] = mx1; }
  __syncthreads();
  float M0 = redM[l31], M1 = redM[32 + l31];
#pragma unroll
  for (int w = 1; w < 8; ++w) {
    M0 = fmaxf(M0, redM[w * 64 + l31]);
    M1 = fmaxf(M1, redM[w * 64 + 32 + l31]);
  }
  float s0 = 0.f, s1 = 0.f;
#pragma unroll
  for (int mt = 0; mt < 4; ++mt)
#pragma unroll
    for (int reg = 0; reg < 16; ++reg) {
      const float e0 = __expf(acc[mt][0][reg] - M0);
      const float e1 = __expf(acc[mt][1][reg] - M1);
      acc[mt][0][reg] = e0; acc[mt][1][reg] = e1;
      s0 += e0; s1 += e1;
    }
  s0 += __shfl_xor(s0, 32);
  s1 += __shfl_xor(s1, 32);
  if (lane < 32) { redS[wv * 64 + l31] = s0; redS[wv * 64 + 32 + l31] = s1; }
  __syncthreads();
  float S0 = redS[l31], S1 = redS[32 + l31];
#pragma unroll
  for (int w = 1; w < 8; ++w) {
    S0 += redS[w * 64 + l31];
    S1 += redS[w * 64 + 32 + l31];
  }
  const float r0 = 1.0f / S0, r1 = 1.0f / S1;

  float* const outb = out + ((size_t)bb << 21);   // b * 1024 * 2048
  const int tc0 = t00 + l31, tc1 = t00 + 32 + l31;
#pragma unroll
  for (int mt = 0; mt < 4; ++mt) {
    const int sb = sw * 128 + mt * 32 + lhi * 4;
#pragma unroll
    for (int q = 0; q < 4; ++q)
#pragma unroll
      for (int r = 0; r < 4; ++r) {
        const int srow = sb + q * 8 + r;
        const int reg = q * 4 + r;
        outb[(size_t)srow * T_DIM + tc0] = acc[mt][0][reg] * r0;
        outb[(size_t)srow * T_DIM + tc1] = acc[mt][1][reg] * r1;
      }
  }
}

// ---------------- launch ----------------
extern "C" void kernel_launch(void* const* d_in, const int* in_sizes, int n_in,
                              void* d_out, int out_size, void* d_ws, size_t ws_size,
                              hipStream_t stream) {
  (void)in_sizes; (void)n_in; (void)out_size; (void)ws_size;
  const float* H = (const float*)d_in[0];
  const float* units = (const float*)d_in[1];
  float* out = (float*)d_out;
  char* ws = (char*)d_ws;
  u16* BpH = (u16*)(ws);
  u16* BpL = (u16*)(ws + 134217728);
  u16* UpH = (u16*)(ws + 268435456);
  u16* UpL = (u16*)(ws + 269484032);
  float* msq = (float*)(ws + 270532608);

  k_prep_units<<<dim3(S_DIM / 4), 256, 0, stream>>>(units, UpH, UpL, msq);
  k_prep_h<<<dim3(T_DIM / 64, DIM / 64, B_DIM), 256, 0, stream>>>(H, BpH, BpL);
  k_fused<<<dim3(T_DIM / 64, B_DIM), 512, 0, stream>>>(UpH, UpL, BpH, BpL, msq, out);
}